// Round 1
// baseline (121.985 us; speedup 1.0000x reference)
//
#include <hip/hip_runtime.h>
#include <math.h>

// Problem constants
#define BB 4096      // batch
#define NE 8         // experts
#define NP 256       // patches
#define NK 16        // patch dim
#define NF 64        // filter size
#define ROW 4096     // NP*NK floats per batch row

// ws float layout:
//   [0,256)          W[e][j][k]  (e*32 + j*16 + k)
//   [256,272)        Bsum[e][j]  (e*2 + j)
//   [272, 272+8192)  hpart[block][e]   (1024 blocks)
//   [8464, 16656)    mpart[block][e]
#define WS_W 0
#define WS_B 256
#define WS_H 272
#define WS_M 8464
#define NBLK 1024

__global__ __launch_bounds__(256) void prep_kernel(const float* __restrict__ ew,
                                                   const float* __restrict__ eb,
                                                   float* __restrict__ ws) {
    int t = threadIdx.x;  // 256 threads
    // W[e][j][k] = sum_f ew[e, j*64+f, k]
    int e = t >> 5, j = (t >> 4) & 1, k = t & 15;
    const float* base = ew + e * (128 * 16) + j * (64 * 16) + k;
    float s = 0.f;
#pragma unroll
    for (int f = 0; f < 64; ++f) s += base[f * 16];
    ws[WS_W + t] = s;
    if (t < 16) {
        int e2 = t >> 1, j2 = t & 1;
        const float* bb = eb + e2 * 128 + j2 * 64;
        float sb = 0.f;
#pragma unroll
        for (int f = 0; f < 64; ++f) sb += bb[f];
        ws[WS_B + t] = sb;
    }
}

__global__ __launch_bounds__(256) void main_kernel(const float* __restrict__ x,
                                                   const float* __restrict__ noise,
                                                   const float* __restrict__ gw,
                                                   const float* __restrict__ gb,
                                                   const float* __restrict__ ws,
                                                   float* __restrict__ out,
                                                   float* __restrict__ hpart,
                                                   float* __restrict__ mpart) {
    __shared__ float s_sh[4][16];
    __shared__ float hacc[8];
    __shared__ float macc[8];
    int tid = threadIdx.x;
    if (tid < 8) { hacc[tid] = 0.f; macc[tid] = 0.f; }
    __syncthreads();

    int wave = tid >> 6;
    int lane = tid & 63;
    int b = blockIdx.x * 4 + wave;

    // --- row reduction: s[b,k] = sum_p x[b, p*16+k] ---
    const float4* xb = (const float4*)(x + (size_t)b * ROW);
    float4 acc = make_float4(0.f, 0.f, 0.f, 0.f);
#pragma unroll
    for (int t = 0; t < 16; ++t) {
        float4 v = xb[lane + 64 * t];
        acc.x += v.x; acc.y += v.y; acc.z += v.z; acc.w += v.w;
    }
    // lane's float4 covers buckets 4*(lane&3) + {0..3}; reduce lanes sharing lane&3
#pragma unroll
    for (int m = 4; m <= 32; m <<= 1) {
        acc.x += __shfl_xor(acc.x, m);
        acc.y += __shfl_xor(acc.y, m);
        acc.z += __shfl_xor(acc.z, m);
        acc.w += __shfl_xor(acc.w, m);
    }
    if (lane < 4) {
        s_sh[wave][4 * lane + 0] = acc.x;
        s_sh[wave][4 * lane + 1] = acc.y;
        s_sh[wave][4 * lane + 2] = acc.z;
        s_sh[wave][4 * lane + 3] = acc.w;
    }
    __builtin_amdgcn_wave_barrier();  // wave-internal LDS write->read ordering

    // --- gating: lanes 0..7 compute h[b,e] for e=lane ---
    float hv = -3.0e38f;
    if (lane < 8) {
        const float* gwr = gw + lane * NK;
        float d = 0.f;
#pragma unroll
        for (int k = 0; k < NK; ++k) d += s_sh[wave][k] * gwr[k];
        hv = d + 256.f * gb[lane] + noise[b];
    }
    // argmax (first-index tie-break) across lanes 0..7
    float mv = hv;
    int mi = lane & 7;
#pragma unroll
    for (int m = 1; m <= 4; m <<= 1) {
        float ov = __shfl_xor(mv, m);
        int oi = __shfl_xor(mi, m);
        if (ov > mv || (ov == mv && oi < mi)) { mv = ov; mi = oi; }
    }
    // now lanes 0..7 hold pi_val=mv, e*=mi

    if (lane == 0) {
        const float* Wr = ws + WS_W + mi * 32;
        const float* Bs = ws + WS_B + mi * 2;
        float o0 = 0.f, o1 = 0.f;
#pragma unroll
        for (int k = 0; k < NK; ++k) {
            float sv = s_sh[wave][k];
            o0 += sv * Wr[k];
            o1 += sv * Wr[16 + k];
        }
        o0 = mv * (o0 + 256.f * Bs[0]);
        o1 = mv * (o1 + 256.f * Bs[1]);
        out[b * 2 + 0] = o0;
        out[b * 2 + 1] = o1;
    }
    if (lane < 8) {
        float mk = (lane == mi) ? 1.f : 0.f;
        out[2 * BB + b * 8 + lane] = mk;   // mask output
        atomicAdd(&hacc[lane], hv);
        atomicAdd(&macc[lane], mk);
    }
    __syncthreads();
    if (tid < 8) {
        hpart[blockIdx.x * 8 + tid] = hacc[tid];
        mpart[blockIdx.x * 8 + tid] = macc[tid];
    }
}

__global__ __launch_bounds__(256) void loss_kernel(const float* __restrict__ hpart,
                                                   const float* __restrict__ mpart,
                                                   float* __restrict__ out) {
    __shared__ float hs[256], ms[256];
    int t = threadIdx.x;
    int e = t & 7, c = t >> 3;  // 32 chunks of 32 blocks
    float hsum = 0.f, msum = 0.f;
    for (int i = c; i < NBLK; i += 32) {
        hsum += hpart[i * 8 + e];
        msum += mpart[i * 8 + e];
    }
    hs[t] = hsum;
    ms[t] = msum;
    __syncthreads();
    if (t < 8) {
        float hh = 0.f, mm = 0.f;
        for (int c2 = 0; c2 < 32; ++c2) { hh += hs[c2 * 8 + t]; mm += ms[c2 * 8 + t]; }
        hs[t] = hh;
        ms[t] = mm;
    }
    __syncthreads();
    if (t == 0) {
        float loss = 0.f;
        for (int e2 = 0; e2 < 8; ++e2)
            loss += (hs[e2] / 4096.f) * (ms[e2] / 4096.f);
        out[2 * BB + 8 * BB] = loss * 8.f;  // index 40960
    }
}

extern "C" void kernel_launch(void* const* d_in, const int* in_sizes, int n_in,
                              void* d_out, int out_size, void* d_ws, size_t ws_size,
                              hipStream_t stream) {
    const float* x     = (const float*)d_in[0];
    const float* noise = (const float*)d_in[1];
    const float* gw    = (const float*)d_in[2];
    const float* gb    = (const float*)d_in[3];
    const float* ew    = (const float*)d_in[4];
    const float* eb    = (const float*)d_in[5];
    float* out = (float*)d_out;
    float* ws  = (float*)d_ws;

    prep_kernel<<<1, 256, 0, stream>>>(ew, eb, ws);
    main_kernel<<<NBLK, 256, 0, stream>>>(x, noise, gw, gb, ws, out,
                                          ws + WS_H, ws + WS_M);
    loss_kernel<<<1, 256, 0, stream>>>(ws + WS_H, ws + WS_M, out);
}